// Round 4
// baseline (285.845 us; speedup 1.0000x reference)
//
#include <hip/hip_runtime.h>
#include <hip/hip_bf16.h>

#define N_X    65536
#define N_IND  1024
#define N_DESC 64
#define NCHUNK 4
#define CHUNK  (N_IND / NCHUNK)   // 256 inducing points per i-chunk
#define TILES  (CHUNK / 16)       // 16 MFMA row-tiles per chunk
#define L2E    1.4426950408889634f
#define L2E2   2.8853900817779268f

typedef __attribute__((ext_vector_type(8))) short  short8;
typedef __attribute__((ext_vector_type(4))) float  f32x4;

static __device__ __forceinline__ ushort f2bf(float f) {
    union { float f; unsigned u; } a; a.f = f;
    unsigned r = a.u + 0x7FFF + ((a.u >> 16) & 1);   // RNE to bf16
    return (ushort)(r >> 16);
}
static __device__ __forceinline__ float bf2f(ushort h) {
    union { unsigned u; float f; } a; a.u = (unsigned)h << 16;
    return a.f;
}

// ---------------------------------------------------------------------------
// prep_z: zwb[i][k] = bf16(z[i][k]*exp(-ls[k]/2));  zs2[i] = log2e*sum(zw^2)
// 4 lanes per row (16 k each), shfl-reduce the square sum. Tiny kernel.
// ---------------------------------------------------------------------------
__global__ __launch_bounds__(256) void igpr_prep_z(
        const float* __restrict__ z, const float* __restrict__ ls,
        ushort* __restrict__ zwb, float* __restrict__ zs2) {
    int tid = blockIdx.x * 256 + threadIdx.x;
    int r = tid >> 2, q = tid & 3;
    if (r >= N_IND) return;
    float sq = 0.f;
    ushort hb[16];
#pragma unroll
    for (int m = 0; m < 4; ++m) {
        float4 v = *reinterpret_cast<const float4*>(&z[r * N_DESC + q * 16 + m * 4]);
        float vv[4] = {v.x, v.y, v.z, v.w};
#pragma unroll
        for (int e = 0; e < 4; ++e) {
            float w = __expf(-0.5f * ls[q * 16 + m * 4 + e]);
            ushort h = f2bf(vv[e] * w);
            hb[m * 4 + e] = h;
            float vr = bf2f(h);
            sq = fmaf(vr, vr, sq);
        }
    }
    unsigned u[8];
#pragma unroll
    for (int t = 0; t < 8; ++t)
        u[t] = (unsigned)hb[2 * t] | ((unsigned)hb[2 * t + 1] << 16);
    uint4* d4 = reinterpret_cast<uint4*>(&zwb[r * N_DESC + q * 16]);
    d4[0] = make_uint4(u[0], u[1], u[2], u[3]);
    d4[1] = make_uint4(u[4], u[5], u[6], u[7]);
    sq += __shfl_xor(sq, 1);
    sq += __shfl_xor(sq, 2);
    if (q == 0) zs2[r] = sq * L2E;
}

// ---------------------------------------------------------------------------
// main: wave owns 64 x-columns (4 strips of 16). x converted to bf16
// in-register (x stays a CLEAN input -> cacheable; no ws round-trip).
// Per tile: 8 independent MFMAs (split accumulators), A/zs2/alpha
// prefetched one tile ahead. launch_bounds(256,4) caps VGPR at 128 ->
// 4 waves/SIMD, the whole (256,4)-grid resident in one generation.
// ---------------------------------------------------------------------------
__global__ __launch_bounds__(256, 4) void igpr_main(
        const float* __restrict__ x, const float* __restrict__ ls,
        const ushort* __restrict__ zwb, const float* __restrict__ zs2,
        const float* __restrict__ alpha, float* __restrict__ part) {
    const int lane = threadIdx.x & 63;
    const int wave = threadIdx.x >> 6;
    const int p = lane & 15;          // point index within strip
    const int g = lane >> 4;          // k-group
    const int j0 = blockIdx.x * 256 + wave * 64;
    const int c  = blockIdx.y;        // i-chunk

    // per-lane lengthscale weights for its 16 k's
    float wk[16];
#pragma unroll
    for (int h = 0; h < 2; ++h) {
        float4 w0 = *reinterpret_cast<const float4*>(&ls[h * 32 + g * 8]);
        float4 w1 = *reinterpret_cast<const float4*>(&ls[h * 32 + g * 8 + 4]);
        float wv[8] = {w0.x, w0.y, w0.z, w0.w, w1.x, w1.y, w1.z, w1.w};
#pragma unroll
        for (int e = 0; e < 8; ++e)
            wk[h * 8 + e] = __expf(-0.5f * wv[e]);
    }

    // B fragments (xw bf16) + per-column log2e*x_sq; strips serialized with
    // sched_barrier so the compiler doesn't keep 64 floats in flight.
    short8 b[4][2];
    float xs2v[4];
#pragma unroll
    for (int s = 0; s < 4; ++s) {
        const float* xr = x + (size_t)(j0 + s * 16 + p) * N_DESC;
        float sq = 0.f;
#pragma unroll
        for (int h = 0; h < 2; ++h) {
            float4 v0 = *reinterpret_cast<const float4*>(xr + h * 32 + g * 8);
            float4 v1 = *reinterpret_cast<const float4*>(xr + h * 32 + g * 8 + 4);
            float vv[8] = {v0.x, v0.y, v0.z, v0.w, v1.x, v1.y, v1.z, v1.w};
            short8 bb;
#pragma unroll
            for (int e = 0; e < 8; ++e) {
                ushort hh = f2bf(vv[e] * wk[h * 8 + e]);
                bb[e] = (short)hh;
                float xv = bf2f(hh);
                sq = fmaf(xv, xv, sq);
            }
            b[s][h] = bb;
        }
        sq += __shfl_xor(sq, 16);
        sq += __shfl_xor(sq, 32);
        xs2v[s] = sq * L2E;
        __builtin_amdgcn_sched_barrier(0);
    }

    float accJ[4] = {0.f, 0.f, 0.f, 0.f};
    const int ibase = c * CHUNK;

    // prefetch tile 0: A-frags + epilogue vectors
    const ushort* zr0 = zwb + (size_t)(ibase + p) * N_DESC;
    short8 a0 = *reinterpret_cast<const short8*>(zr0 + g * 8);
    short8 a1 = *reinterpret_cast<const short8*>(zr0 + 32 + g * 8);
    float4 z2 = *reinterpret_cast<const float4*>(&zs2[ibase + g * 4]);
    float4 a4 = *reinterpret_cast<const float4*>(&alpha[ibase + g * 4]);

    for (int it = 0; it < TILES; ++it) {
        short8 ca0 = a0, ca1 = a1;
        float z2v[4] = {z2.x, z2.y, z2.z, z2.w};
        float a4v[4] = {a4.x, a4.y, a4.z, a4.w};

        if (it + 1 < TILES) {
            const int i1 = ibase + (it + 1) * 16;
            const ushort* nzr = zwb + (size_t)(i1 + p) * N_DESC;
            a0 = *reinterpret_cast<const short8*>(nzr + g * 8);
            a1 = *reinterpret_cast<const short8*>(nzr + 32 + g * 8);
            z2 = *reinterpret_cast<const float4*>(&zs2[i1 + g * 4]);
            a4 = *reinterpret_cast<const float4*>(&alpha[i1 + g * 4]);
        }

        f32x4 acc0[4], acc1[4];
#pragma unroll
        for (int s = 0; s < 4; ++s) {
            f32x4 t0 = {0.f, 0.f, 0.f, 0.f};
            f32x4 t1 = {0.f, 0.f, 0.f, 0.f};
            acc0[s] = __builtin_amdgcn_mfma_f32_16x16x32_bf16(ca0, b[s][0], t0, 0, 0, 0);
            acc1[s] = __builtin_amdgcn_mfma_f32_16x16x32_bf16(ca1, b[s][1], t1, 0, 0, 0);
        }

#pragma unroll
        for (int s = 0; s < 4; ++s) {
#pragma unroll
            for (int e = 0; e < 4; ++e) {
                float dot = acc0[s][e] + acc1[s][e];
                float arg = fmaf(dot, L2E2, -(z2v[e] + xs2v[s]));
                float pv  = __builtin_amdgcn_exp2f(arg);
                accJ[s]   = fmaf(a4v[e], pv, accJ[s]);
            }
        }
    }

#pragma unroll
    for (int s = 0; s < 4; ++s) {
        float r = accJ[s];
        r += __shfl_xor(r, 16);
        r += __shfl_xor(r, 32);
        if (g == 0) part[(size_t)c * N_X + j0 + s * 16 + p] = r;
    }
}

// ---------------------------------------------------------------------------
// reduce: out[j] = sum_c part[c][j]
// ---------------------------------------------------------------------------
__global__ void igpr_reduce(const float* __restrict__ part,
                            float* __restrict__ out) {
    int j = blockIdx.x * 256 + threadIdx.x;
    float s = 0.f;
#pragma unroll
    for (int c = 0; c < NCHUNK; ++c) s += part[(size_t)c * N_X + j];
    out[j] = s;
}

extern "C" void kernel_launch(void* const* d_in, const int* in_sizes, int n_in,
                              void* d_out, int out_size, void* d_ws, size_t ws_size,
                              hipStream_t stream) {
    const float* x     = (const float*)d_in[0];   // (65536, 64)
    const float* z     = (const float*)d_in[1];   // (1024, 64)
    const float* alpha = (const float*)d_in[2];   // (1024,)
    const float* ls    = (const float*)d_in[3];   // (64,)
    float* out = (float*)d_out;                   // (65536, 1)

    // ws layout: zwb ushort[1024*64] (128 KB) | zs2 f32[1024] | part f32[4*65536]
    ushort* zwb  = (ushort*)d_ws;
    float*  zs2  = (float*)(zwb + (size_t)N_IND * N_DESC);
    float*  part = zs2 + N_IND;

    igpr_prep_z<<<dim3(16), dim3(256), 0, stream>>>(z, ls, zwb, zs2);
    igpr_main<<<dim3(N_X / 256, NCHUNK), dim3(256), 0, stream>>>(x, ls, zwb, zs2, alpha, part);
    igpr_reduce<<<dim3(N_X / 256), dim3(256), 0, stream>>>(part, out);
}

// Round 5
// 84.883 us; speedup vs baseline: 3.3675x; 3.3675x over previous
//
#include <hip/hip_runtime.h>
#include <hip/hip_bf16.h>

#define N_X    65536
#define N_IND  1024
#define N_DESC 64
#define NCHUNK 2
#define CHUNK  (N_IND / NCHUNK)   // 512 inducing points per i-chunk
#define TILES  (CHUNK / 16)       // 32 MFMA row-tiles per chunk
#define STRIPS 2                  // 32 x-columns per wave
#define L2E    1.4426950408889634f
#define L2E2   2.8853900817779268f

typedef __attribute__((ext_vector_type(8))) short  short8;
typedef __attribute__((ext_vector_type(4))) float  f32x4;

static __device__ __forceinline__ ushort f2bf(float f) {
    union { float f; unsigned u; } a; a.f = f;
    unsigned r = a.u + 0x7FFF + ((a.u >> 16) & 1);   // RNE to bf16
    return (ushort)(r >> 16);
}
static __device__ __forceinline__ float bf2f(ushort h) {
    union { unsigned u; float f; } a; a.u = (unsigned)h << 16;
    return a.f;
}

// ---------------------------------------------------------------------------
// prep_z: zwb[i][k] = bf16(z[i][k]*exp(-ls[k]/2));  zs2[i] = log2e*sum(zw^2)
// ---------------------------------------------------------------------------
__global__ __launch_bounds__(256) void igpr_prep_z(
        const float* __restrict__ z, const float* __restrict__ ls,
        ushort* __restrict__ zwb, float* __restrict__ zs2) {
    int tid = blockIdx.x * 256 + threadIdx.x;
    int r = tid >> 2, q = tid & 3;
    if (r >= N_IND) return;
    float sq = 0.f;
    ushort hb[16];
#pragma unroll
    for (int m = 0; m < 4; ++m) {
        float4 v = *reinterpret_cast<const float4*>(&z[r * N_DESC + q * 16 + m * 4]);
        float vv[4] = {v.x, v.y, v.z, v.w};
#pragma unroll
        for (int e = 0; e < 4; ++e) {
            float w = __expf(-0.5f * ls[q * 16 + m * 4 + e]);
            ushort h = f2bf(vv[e] * w);
            hb[m * 4 + e] = h;
            float vr = bf2f(h);
            sq = fmaf(vr, vr, sq);
        }
    }
    unsigned u[8];
#pragma unroll
    for (int t = 0; t < 8; ++t)
        u[t] = (unsigned)hb[2 * t] | ((unsigned)hb[2 * t + 1] << 16);
    uint4* d4 = reinterpret_cast<uint4*>(&zwb[r * N_DESC + q * 16]);
    d4[0] = make_uint4(u[0], u[1], u[2], u[3]);
    d4[1] = make_uint4(u[4], u[5], u[6], u[7]);
    sq += __shfl_xor(sq, 1);
    sq += __shfl_xor(sq, 2);
    if (q == 0) zs2[r] = sq * L2E;
}

// ---------------------------------------------------------------------------
// main: wave owns 32 x-columns (2 strips of 16). x converted to bf16
// in-register (x stays a clean, cacheable input). 2-slot register ring for
// A-frags + zs2/alpha, statically indexed (2x-unrolled loop); prefetch is
// issued LAST in each phase (after the epilogue consumes the slot) so the
// in-flight load covers the next phase. No forced occupancy bound — round 4
// showed launch_bounds(.,4) on this structure spills to scratch.
// C/D layout: col = lane&15, row = 4*(lane>>4) + reg.
// ---------------------------------------------------------------------------
__global__ __launch_bounds__(256) void igpr_main(
        const float* __restrict__ x, const float* __restrict__ ls,
        const ushort* __restrict__ zwb, const float* __restrict__ zs2,
        const float* __restrict__ alpha, float* __restrict__ part) {
    const int lane = threadIdx.x & 63;
    const int wave = threadIdx.x >> 6;
    const int p = lane & 15;          // point index within strip
    const int g = lane >> 4;          // k-group
    const int j0 = blockIdx.x * (64 * STRIPS * 2) + wave * (16 * STRIPS);
    const int c  = blockIdx.y;        // i-chunk

    // per-lane lengthscale weights for its 16 k's
    float wk[16];
#pragma unroll
    for (int h = 0; h < 2; ++h) {
        float4 w0 = *reinterpret_cast<const float4*>(&ls[h * 32 + g * 8]);
        float4 w1 = *reinterpret_cast<const float4*>(&ls[h * 32 + g * 8 + 4]);
        float wv[8] = {w0.x, w0.y, w0.z, w0.w, w1.x, w1.y, w1.z, w1.w};
#pragma unroll
        for (int e = 0; e < 8; ++e)
            wk[h * 8 + e] = __expf(-0.5f * wv[e]);
    }

    // B fragments (xw bf16) + per-column log2e*x_sq
    short8 b[STRIPS][2];
    float xs2v[STRIPS];
#pragma unroll
    for (int s = 0; s < STRIPS; ++s) {
        const float* xr = x + (size_t)(j0 + s * 16 + p) * N_DESC;
        float sq = 0.f;
#pragma unroll
        for (int h = 0; h < 2; ++h) {
            float4 v0 = *reinterpret_cast<const float4*>(xr + h * 32 + g * 8);
            float4 v1 = *reinterpret_cast<const float4*>(xr + h * 32 + g * 8 + 4);
            float vv[8] = {v0.x, v0.y, v0.z, v0.w, v1.x, v1.y, v1.z, v1.w};
            short8 bb;
#pragma unroll
            for (int e = 0; e < 8; ++e) {
                ushort hh = f2bf(vv[e] * wk[h * 8 + e]);
                bb[e] = (short)hh;
                float xv = bf2f(hh);
                sq = fmaf(xv, xv, sq);
            }
            b[s][h] = bb;
        }
        sq += __shfl_xor(sq, 16);
        sq += __shfl_xor(sq, 32);
        xs2v[s] = sq * L2E;
    }

    float accJ[STRIPS] = {0.f, 0.f};
    const int ibase = c * CHUNK;

    // 2-slot ring, named registers (rule #20: no runtime-indexed arrays)
    short8 A0_0, A1_0, A0_1, A1_1;
    float4 Z_0, AL_0, Z_1, AL_1;

#define LOADA(ti, A0s, A1s, Zs, ALs)                                          \
    {                                                                         \
        const int i0_ = ibase + (ti) * 16;                                    \
        const ushort* zr_ = zwb + (size_t)(i0_ + p) * N_DESC;                 \
        A0s = *reinterpret_cast<const short8*>(zr_ + g * 8);                  \
        A1s = *reinterpret_cast<const short8*>(zr_ + 32 + g * 8);             \
        Zs  = *reinterpret_cast<const float4*>(&zs2[i0_ + g * 4]);            \
        ALs = *reinterpret_cast<const float4*>(&alpha[i0_ + g * 4]);          \
    }

#define PHASE(A0s, A1s, Zs, ALs)                                              \
    {                                                                         \
        f32x4 acc0[STRIPS], acc1[STRIPS];                                     \
        _Pragma("unroll")                                                     \
        for (int s = 0; s < STRIPS; ++s) {                                    \
            f32x4 t0 = {0.f, 0.f, 0.f, 0.f};                                  \
            f32x4 t1 = {0.f, 0.f, 0.f, 0.f};                                  \
            acc0[s] = __builtin_amdgcn_mfma_f32_16x16x32_bf16(A0s, b[s][0], t0, 0, 0, 0); \
            acc1[s] = __builtin_amdgcn_mfma_f32_16x16x32_bf16(A1s, b[s][1], t1, 0, 0, 0); \
        }                                                                     \
        float z2v_[4] = {Zs.x, Zs.y, Zs.z, Zs.w};                             \
        float a4v_[4] = {ALs.x, ALs.y, ALs.z, ALs.w};                         \
        _Pragma("unroll")                                                     \
        for (int s = 0; s < STRIPS; ++s) {                                    \
            _Pragma("unroll")                                                 \
            for (int e = 0; e < 4; ++e) {                                     \
                float dot = acc0[s][e] + acc1[s][e];                          \
                float arg = fmaf(dot, L2E2, -(z2v_[e] + xs2v[s]));            \
                float pv  = __builtin_amdgcn_exp2f(arg);                      \
                accJ[s]   = fmaf(a4v_[e], pv, accJ[s]);                       \
            }                                                                 \
        }                                                                     \
    }

    LOADA(0, A0_0, A1_0, Z_0, AL_0);
    LOADA(1, A0_1, A1_1, Z_1, AL_1);

    for (int it = 0; it < TILES; it += 2) {
        // phase 0: consume slot0 (tile it); refill with tile it+2
        PHASE(A0_0, A1_0, Z_0, AL_0);
        {
            int ip = (it + 2 < TILES) ? it + 2 : it;   // uniform, harmless refill
            LOADA(ip, A0_0, A1_0, Z_0, AL_0);
        }
        // phase 1: consume slot1 (tile it+1); refill with tile it+3
        PHASE(A0_1, A1_1, Z_1, AL_1);
        {
            int ip = (it + 3 < TILES) ? it + 3 : it + 1;
            LOADA(ip, A0_1, A1_1, Z_1, AL_1);
        }
    }
#undef LOADA
#undef PHASE

#pragma unroll
    for (int s = 0; s < STRIPS; ++s) {
        float r = accJ[s];
        r += __shfl_xor(r, 16);
        r += __shfl_xor(r, 32);
        if (g == 0) part[(size_t)c * N_X + j0 + s * 16 + p] = r;
    }
}

// ---------------------------------------------------------------------------
// reduce: out[j] = sum_c part[c][j]
// ---------------------------------------------------------------------------
__global__ void igpr_reduce(const float* __restrict__ part,
                            float* __restrict__ out) {
    int j = blockIdx.x * 256 + threadIdx.x;
    float s = 0.f;
#pragma unroll
    for (int c = 0; c < NCHUNK; ++c) s += part[(size_t)c * N_X + j];
    out[j] = s;
}

extern "C" void kernel_launch(void* const* d_in, const int* in_sizes, int n_in,
                              void* d_out, int out_size, void* d_ws, size_t ws_size,
                              hipStream_t stream) {
    const float* x     = (const float*)d_in[0];   // (65536, 64)
    const float* z     = (const float*)d_in[1];   // (1024, 64)
    const float* alpha = (const float*)d_in[2];   // (1024,)
    const float* ls    = (const float*)d_in[3];   // (64,)
    float* out = (float*)d_out;                   // (65536, 1)

    // ws layout: zwb ushort[1024*64] (128 KB) | zs2 f32[1024] | part f32[NCHUNK*65536]
    ushort* zwb  = (ushort*)d_ws;
    float*  zs2  = (float*)(zwb + (size_t)N_IND * N_DESC);
    float*  part = zs2 + N_IND;

    igpr_prep_z<<<dim3(16), dim3(256), 0, stream>>>(z, ls, zwb, zs2);
    igpr_main<<<dim3(N_X / (64 * STRIPS * 2), NCHUNK), dim3(256), 0, stream>>>(
        x, ls, zwb, zs2, alpha, part);
    igpr_reduce<<<dim3(N_X / 256), dim3(256), 0, stream>>>(part, out);
}

// Round 6
// 36.202 us; speedup vs baseline: 7.8959x; 2.3447x over previous
//
#include <hip/hip_runtime.h>
#include <hip/hip_bf16.h>

#define N_X    65536
#define N_IND  1024
#define N_DESC 64
#define NCHUNK 4
#define CHUNK  (N_IND / NCHUNK)   // 256 inducing points per i-chunk
#define TILES  (CHUNK / 16)       // 16 MFMA row-tiles per chunk
#define L2E    1.4426950408889634f
#define L2E2   2.8853900817779268f

typedef __attribute__((ext_vector_type(8))) short  short8;
typedef __attribute__((ext_vector_type(4))) float  f32x4;

static __device__ __forceinline__ ushort f2bf(float f) {
    union { float f; unsigned u; } a; a.f = f;
    unsigned r = a.u + 0x7FFF + ((a.u >> 16) & 1);   // RNE to bf16
    return (ushort)(r >> 16);
}
static __device__ __forceinline__ float bf2f(ushort h) {
    union { unsigned u; float f; } a; a.u = (unsigned)h << 16;
    return a.f;
}

// ---------------------------------------------------------------------------
// prep_z: zwb[i][k] = bf16(z[i][k]*exp(-ls[k]/2));  zs2[i] = log2e*sum(zw^2)
// ---------------------------------------------------------------------------
__global__ __launch_bounds__(256) void igpr_prep_z(
        const float* __restrict__ z, const float* __restrict__ ls,
        ushort* __restrict__ zwb, float* __restrict__ zs2) {
    int tid = blockIdx.x * 256 + threadIdx.x;
    int r = tid >> 2, q = tid & 3;
    if (r >= N_IND) return;
    float sq = 0.f;
    ushort hb[16];
#pragma unroll
    for (int m = 0; m < 4; ++m) {
        float4 v = *reinterpret_cast<const float4*>(&z[r * N_DESC + q * 16 + m * 4]);
        float vv[4] = {v.x, v.y, v.z, v.w};
#pragma unroll
        for (int e = 0; e < 4; ++e) {
            float w = __expf(-0.5f * ls[q * 16 + m * 4 + e]);
            ushort h = f2bf(vv[e] * w);
            hb[m * 4 + e] = h;
            float vr = bf2f(h);
            sq = fmaf(vr, vr, sq);
        }
    }
    unsigned u[8];
#pragma unroll
    for (int t = 0; t < 8; ++t)
        u[t] = (unsigned)hb[2 * t] | ((unsigned)hb[2 * t + 1] << 16);
    uint4* d4 = reinterpret_cast<uint4*>(&zwb[r * N_DESC + q * 16]);
    d4[0] = make_uint4(u[0], u[1], u[2], u[3]);
    d4[1] = make_uint4(u[4], u[5], u[6], u[7]);
    sq += __shfl_xor(sq, 1);
    sq += __shfl_xor(sq, 2);
    if (q == 0) zs2[r] = sq * L2E;
}

// ---------------------------------------------------------------------------
// main: block (4 waves) stages its i-chunk's z-panel (32 KB, XOR-swizzled)
// + zs2/alpha (2 KB) into LDS once; each wave owns 64 x-columns (4 strips),
// converts x->bf16 in-register (x stays a clean cacheable input). Inner
// loop: 2 swizzled ds_read_b128 (A-frags) + 2 broadcast LDS float4 reads +
// 8 independent MFMAs + fused exp2 epilogue. No global loads, no register
// A-pipeline -> low VGPR -> 4 waves/SIMD; LDS latency hidden by TLP.
// Swizzle: byte colb ^= (row&7)<<4 on BOTH write and read (rule #21).
// C/D layout: col = lane&15, row = 4*(lane>>4) + reg.
// ---------------------------------------------------------------------------
__global__ __launch_bounds__(256) void igpr_main(
        const float* __restrict__ x, const float* __restrict__ ls,
        const ushort* __restrict__ zwb, const float* __restrict__ zs2,
        const float* __restrict__ alpha, float* __restrict__ part) {
    struct SM {
        uint4 zt[CHUNK * 8];   // 256 rows * 128 B = 32 KB (swizzled)
        float z2[CHUNK];
        float al[CHUNK];
    };
    __shared__ SM sm;

    const int tid  = threadIdx.x;
    const int lane = tid & 63;
    const int wave = tid >> 6;
    const int p = lane & 15;          // point index within strip / z-row in tile
    const int g = lane >> 4;          // k-group
    const int j0 = blockIdx.x * 256 + wave * 64;
    const int c  = blockIdx.y;        // i-chunk

    // ---- stage z-panel into LDS (coalesced 16B, swizzled dest) ----
    {
        const uint4* zsrc = reinterpret_cast<const uint4*>(
            zwb + (size_t)c * CHUNK * N_DESC);
        char* zb = reinterpret_cast<char*>(sm.zt);
#pragma unroll
        for (int rb = 0; rb < 8; ++rb) {
            int lb   = rb * 256 + tid;            // 16B-block linear index
            int row  = lb >> 3;
            int colb = (lb & 7) * 16;
            int sw   = row * 128 + (colb ^ ((row & 7) << 4));
            *reinterpret_cast<uint4*>(zb + sw) = zsrc[lb];
        }
        sm.z2[tid] = zs2[c * CHUNK + tid];        // CHUNK == blockDim.x
        sm.al[tid] = alpha[c * CHUNK + tid];
    }

    // ---- per-lane lengthscale weights for its 16 k's ----
    float wk[16];
#pragma unroll
    for (int h = 0; h < 2; ++h) {
        float4 w0 = *reinterpret_cast<const float4*>(&ls[h * 32 + g * 8]);
        float4 w1 = *reinterpret_cast<const float4*>(&ls[h * 32 + g * 8 + 4]);
        float wv[8] = {w0.x, w0.y, w0.z, w0.w, w1.x, w1.y, w1.z, w1.w};
#pragma unroll
        for (int e = 0; e < 8; ++e)
            wk[h * 8 + e] = __expf(-0.5f * wv[e]);
    }

    // ---- B fragments (xw bf16) + per-column log2e*x_sq ----
    short8 b[4][2];
    float xs2v[4];
#pragma unroll
    for (int s = 0; s < 4; ++s) {
        const float* xr = x + (size_t)(j0 + s * 16 + p) * N_DESC;
        float sq = 0.f;
#pragma unroll
        for (int h = 0; h < 2; ++h) {
            float4 v0 = *reinterpret_cast<const float4*>(xr + h * 32 + g * 8);
            float4 v1 = *reinterpret_cast<const float4*>(xr + h * 32 + g * 8 + 4);
            float vv[8] = {v0.x, v0.y, v0.z, v0.w, v1.x, v1.y, v1.z, v1.w};
            short8 bb;
#pragma unroll
            for (int e = 0; e < 8; ++e) {
                ushort hh = f2bf(vv[e] * wk[h * 8 + e]);
                bb[e] = (short)hh;
                float xv = bf2f(hh);
                sq = fmaf(xv, xv, sq);
            }
            b[s][h] = bb;
        }
        sq += __shfl_xor(sq, 16);
        sq += __shfl_xor(sq, 32);
        xs2v[s] = sq * L2E;
        __builtin_amdgcn_sched_barrier(0);
    }

    __syncthreads();   // z-panel ready (LDS read-only from here)

    // per-lane swizzled LDS byte offsets for A-frags (row = it*16 + p)
    const char* zb = reinterpret_cast<const char*>(sm.zt);
    const int rb0 = p * 128 + ((16 * g)      ^ ((p & 7) << 4));
    const int rb1 = p * 128 + ((64 + 16 * g) ^ ((p & 7) << 4));

    float accJ[4] = {0.f, 0.f, 0.f, 0.f};

#pragma unroll 2
    for (int it = 0; it < TILES; ++it) {
        short8 a0 = *reinterpret_cast<const short8*>(zb + it * 2048 + rb0);
        short8 a1 = *reinterpret_cast<const short8*>(zb + it * 2048 + rb1);
        float4 z2 = *reinterpret_cast<const float4*>(&sm.z2[it * 16 + g * 4]);
        float4 a4 = *reinterpret_cast<const float4*>(&sm.al[it * 16 + g * 4]);

        f32x4 acc0[4], acc1[4];
#pragma unroll
        for (int s = 0; s < 4; ++s) {
            f32x4 t0 = {0.f, 0.f, 0.f, 0.f};
            f32x4 t1 = {0.f, 0.f, 0.f, 0.f};
            acc0[s] = __builtin_amdgcn_mfma_f32_16x16x32_bf16(a0, b[s][0], t0, 0, 0, 0);
            acc1[s] = __builtin_amdgcn_mfma_f32_16x16x32_bf16(a1, b[s][1], t1, 0, 0, 0);
        }

        float z2v[4] = {z2.x, z2.y, z2.z, z2.w};
        float a4v[4] = {a4.x, a4.y, a4.z, a4.w};
#pragma unroll
        for (int s = 0; s < 4; ++s) {
#pragma unroll
            for (int e = 0; e < 4; ++e) {
                float dot = acc0[s][e] + acc1[s][e];
                float arg = fmaf(dot, L2E2, -(z2v[e] + xs2v[s]));
                float pv  = __builtin_amdgcn_exp2f(arg);
                accJ[s]   = fmaf(a4v[e], pv, accJ[s]);
            }
        }
    }

#pragma unroll
    for (int s = 0; s < 4; ++s) {
        float r = accJ[s];
        r += __shfl_xor(r, 16);
        r += __shfl_xor(r, 32);
        if (g == 0) part[(size_t)c * N_X + j0 + s * 16 + p] = r;
    }
}

// ---------------------------------------------------------------------------
// reduce: out[j] = sum_c part[c][j]
// ---------------------------------------------------------------------------
__global__ void igpr_reduce(const float* __restrict__ part,
                            float* __restrict__ out) {
    int j = blockIdx.x * 256 + threadIdx.x;
    float s = 0.f;
#pragma unroll
    for (int c = 0; c < NCHUNK; ++c) s += part[(size_t)c * N_X + j];
    out[j] = s;
}

extern "C" void kernel_launch(void* const* d_in, const int* in_sizes, int n_in,
                              void* d_out, int out_size, void* d_ws, size_t ws_size,
                              hipStream_t stream) {
    const float* x     = (const float*)d_in[0];   // (65536, 64)
    const float* z     = (const float*)d_in[1];   // (1024, 64)
    const float* alpha = (const float*)d_in[2];   // (1024,)
    const float* ls    = (const float*)d_in[3];   // (64,)
    float* out = (float*)d_out;                   // (65536, 1)

    // ws layout: zwb ushort[1024*64] (128 KB) | zs2 f32[1024] | part f32[4*65536]
    ushort* zwb  = (ushort*)d_ws;
    float*  zs2  = (float*)(zwb + (size_t)N_IND * N_DESC);
    float*  part = zs2 + N_IND;

    igpr_prep_z<<<dim3(16), dim3(256), 0, stream>>>(z, ls, zwb, zs2);
    igpr_main<<<dim3(N_X / 256, NCHUNK), dim3(256), 0, stream>>>(
        x, ls, zwb, zs2, alpha, part);
    igpr_reduce<<<dim3(N_X / 256), dim3(256), 0, stream>>>(part, out);
}

// Round 7
// 30.816 us; speedup vs baseline: 9.2758x; 1.1748x over previous
//
#include <hip/hip_runtime.h>
#include <hip/hip_bf16.h>

#define N_X    65536
#define N_IND  1024
#define N_DESC 64
#define NCHUNK 4
#define CHUNK  (N_IND / NCHUNK)   // 256 inducing points per i-chunk
#define TILES  (CHUNK / 16)       // 16 MFMA row-tiles per chunk
#define L2E    1.4426950408889634f
#define L2E2   2.8853900817779268f

typedef __attribute__((ext_vector_type(8))) short  short8;
typedef __attribute__((ext_vector_type(4))) float  f32x4;
typedef __attribute__((ext_vector_type(2))) float  f32x2;

static __device__ __forceinline__ ushort f2bf(float f) {
    union { float f; unsigned u; } a; a.f = f;
    unsigned r = a.u + 0x7FFF + ((a.u >> 16) & 1);   // RNE to bf16
    return (ushort)(r >> 16);
}
static __device__ __forceinline__ float bf2f(ushort h) {
    union { unsigned u; float f; } a; a.u = (unsigned)h << 16;
    return a.f;
}

// ---------------------------------------------------------------------------
// main (fused): block (4 waves) builds its i-chunk's z-panel DIRECTLY from
// the clean z input (convert f32 -> weighted bf16 in-register, swizzled LDS
// write) — no prep kernel, no ws staging of z. Each wave owns 64 x-columns
// (4 strips of 16), converts x -> bf16 in-register. Inner loop: 2 swizzled
// ds_read_b128 A-frags + 2 broadcast LDS float4 + 8 MFMAs chained in pairs
// + packed-f32 exp2 epilogue. Swizzle: byte colb ^= (row&7)<<4 on BOTH
// write and read (rule #21). C/D layout: col = lane&15, row = 4*(lane>>4)+reg.
// ---------------------------------------------------------------------------
__global__ __launch_bounds__(256) void igpr_main(
        const float* __restrict__ x, const float* __restrict__ z,
        const float* __restrict__ alpha, const float* __restrict__ ls,
        float* __restrict__ part) {
    struct SM {
        uint4 zt[CHUNK * 8];   // 256 rows * 128 B = 32 KB (swizzled)
        float z2[CHUNK];       // log2e * ||zw_i||^2
        float al[CHUNK];       // alpha
        float wls[N_DESC];     // exp(-ls/2)
    };
    __shared__ SM sm;

    const int tid  = threadIdx.x;
    const int lane = tid & 63;
    const int wave = tid >> 6;
    const int p = lane & 15;          // point index within strip / z-row in tile
    const int g = lane >> 4;          // k-group
    const int j0 = blockIdx.x * 256 + wave * 64;
    const int c  = blockIdx.y;        // i-chunk

    if (tid < N_DESC) sm.wls[tid] = __expf(-0.5f * ls[tid]);
    __syncthreads();   // wls ready

    // ---- stage z-chunk into LDS (f32 -> weighted bf16, swizzled dest) ----
    {
        const float* zc = z + (size_t)c * CHUNK * N_DESC;
        char* zb = reinterpret_cast<char*>(sm.zt);
#pragma unroll
        for (int rb = 0; rb < 8; ++rb) {
            int lb  = rb * 256 + tid;        // 16B-output-granule index
            int row = lb >> 3, gr = lb & 7;  // row in chunk, granule in row
            float4 v0 = *reinterpret_cast<const float4*>(&zc[row * 64 + gr * 8]);
            float4 v1 = *reinterpret_cast<const float4*>(&zc[row * 64 + gr * 8 + 4]);
            float vv[8] = {v0.x, v0.y, v0.z, v0.w, v1.x, v1.y, v1.z, v1.w};
            ushort hb[8];
            float sq = 0.f;
#pragma unroll
            for (int e = 0; e < 8; ++e) {
                ushort h = f2bf(vv[e] * sm.wls[gr * 8 + e]);
                hb[e] = h;
                float vr = bf2f(h);
                sq = fmaf(vr, vr, sq);
            }
            uint4 u = make_uint4(
                (unsigned)hb[0] | ((unsigned)hb[1] << 16),
                (unsigned)hb[2] | ((unsigned)hb[3] << 16),
                (unsigned)hb[4] | ((unsigned)hb[5] << 16),
                (unsigned)hb[6] | ((unsigned)hb[7] << 16));
            int sw = row * 128 + ((gr * 16) ^ ((row & 7) << 4));
            *reinterpret_cast<uint4*>(zb + sw) = u;
            // row-sum over the 8 granule-threads (lanes differing in tid&7)
            sq += __shfl_xor(sq, 1);
            sq += __shfl_xor(sq, 2);
            sq += __shfl_xor(sq, 4);
            if (gr == 0) sm.z2[row] = sq * L2E;
        }
        sm.al[tid] = alpha[c * CHUNK + tid];   // CHUNK == blockDim.x
    }

    // ---- per-lane lengthscale weights (from wls broadcast) ----
    float wk[16];
#pragma unroll
    for (int h = 0; h < 2; ++h)
#pragma unroll
        for (int e = 0; e < 8; ++e)
            wk[h * 8 + e] = sm.wls[h * 32 + g * 8 + e];

    // ---- B fragments (xw bf16) + per-column log2e*x_sq ----
    short8 b[4][2];
    float xs2v[4];
#pragma unroll
    for (int s = 0; s < 4; ++s) {
        const float* xr = x + (size_t)(j0 + s * 16 + p) * N_DESC;
        float sq = 0.f;
#pragma unroll
        for (int h = 0; h < 2; ++h) {
            float4 v0 = *reinterpret_cast<const float4*>(xr + h * 32 + g * 8);
            float4 v1 = *reinterpret_cast<const float4*>(xr + h * 32 + g * 8 + 4);
            float vv[8] = {v0.x, v0.y, v0.z, v0.w, v1.x, v1.y, v1.z, v1.w};
            short8 bb;
#pragma unroll
            for (int e = 0; e < 8; ++e) {
                ushort hh = f2bf(vv[e] * wk[h * 8 + e]);
                bb[e] = (short)hh;
                float xv = bf2f(hh);
                sq = fmaf(xv, xv, sq);
            }
            b[s][h] = bb;
        }
        sq += __shfl_xor(sq, 16);
        sq += __shfl_xor(sq, 32);
        xs2v[s] = sq * L2E;
        __builtin_amdgcn_sched_barrier(0);
    }

    __syncthreads();   // z-panel ready (LDS read-only from here)

    const char* zb = reinterpret_cast<const char*>(sm.zt);
    const int rb0 = p * 128 + ((16 * g)      ^ ((p & 7) << 4));
    const int rb1 = p * 128 + ((64 + 16 * g) ^ ((p & 7) << 4));

    f32x2 accJ[4] = {{0.f, 0.f}, {0.f, 0.f}, {0.f, 0.f}, {0.f, 0.f}};

#pragma unroll 2
    for (int it = 0; it < TILES; ++it) {
        short8 a0 = *reinterpret_cast<const short8*>(zb + it * 2048 + rb0);
        short8 a1 = *reinterpret_cast<const short8*>(zb + it * 2048 + rb1);
        float4 z2 = *reinterpret_cast<const float4*>(&sm.z2[it * 16 + g * 4]);
        float4 a4 = *reinterpret_cast<const float4*>(&sm.al[it * 16 + g * 4]);

        f32x4 t[4];
#pragma unroll
        for (int s = 0; s < 4; ++s) {
            f32x4 t0 = {0.f, 0.f, 0.f, 0.f};
            t0 = __builtin_amdgcn_mfma_f32_16x16x32_bf16(a0, b[s][0], t0, 0, 0, 0);
            t[s] = __builtin_amdgcn_mfma_f32_16x16x32_bf16(a1, b[s][1], t0, 0, 0, 0);
        }

        f32x2 z2p[2] = {{z2.x, z2.y}, {z2.z, z2.w}};
        f32x2 a4p[2] = {{a4.x, a4.y}, {a4.z, a4.w}};
#pragma unroll
        for (int s = 0; s < 4; ++s) {
            f32x2 xs2p = {xs2v[s], xs2v[s]};
#pragma unroll
            for (int ep = 0; ep < 2; ++ep) {
                f32x2 dot2 = {t[s][2 * ep], t[s][2 * ep + 1]};
                f32x2 zx   = z2p[ep] + xs2p;               // v_pk_add_f32
                f32x2 arg  = dot2 * L2E2 - zx;             // contracts to pk_fma
                f32x2 pv   = {__builtin_amdgcn_exp2f(arg.x),
                              __builtin_amdgcn_exp2f(arg.y)};
                accJ[s]    = accJ[s] + a4p[ep] * pv;       // contracts to pk_fma
            }
        }
    }

#pragma unroll
    for (int s = 0; s < 4; ++s) {
        float r = accJ[s].x + accJ[s].y;
        r += __shfl_xor(r, 16);
        r += __shfl_xor(r, 32);
        if (g == 0) part[(size_t)c * N_X + j0 + s * 16 + p] = r;
    }
}

// ---------------------------------------------------------------------------
// reduce: out[j] = sum_c part[c][j]
// ---------------------------------------------------------------------------
__global__ void igpr_reduce(const float* __restrict__ part,
                            float* __restrict__ out) {
    int j = blockIdx.x * 256 + threadIdx.x;
    float s = 0.f;
#pragma unroll
    for (int c = 0; c < NCHUNK; ++c) s += part[(size_t)c * N_X + j];
    out[j] = s;
}

extern "C" void kernel_launch(void* const* d_in, const int* in_sizes, int n_in,
                              void* d_out, int out_size, void* d_ws, size_t ws_size,
                              hipStream_t stream) {
    const float* x     = (const float*)d_in[0];   // (65536, 64)
    const float* z     = (const float*)d_in[1];   // (1024, 64)
    const float* alpha = (const float*)d_in[2];   // (1024,)
    const float* ls    = (const float*)d_in[3];   // (64,)
    float* out = (float*)d_out;                   // (65536, 1)

    float* part = (float*)d_ws;                   // f32[NCHUNK * N_X]

    igpr_main<<<dim3(N_X / 256, NCHUNK), dim3(256), 0, stream>>>(
        x, z, alpha, ls, part);
    igpr_reduce<<<dim3(N_X / 256), dim3(256), 0, stream>>>(part, out);
}

// Round 8
// 25.453 us; speedup vs baseline: 11.2305x; 1.2107x over previous
//
#include <hip/hip_runtime.h>
#include <hip/hip_bf16.h>

#define N_X    65536
#define N_IND  1024
#define N_DESC 64
#define TILES  (N_IND / 16)       // 64 MFMA row-tiles (full z-panel)
#define L2E    1.4426950408889634f
#define L2E2   2.8853900817779268f

typedef __attribute__((ext_vector_type(8))) short  short8;
typedef __attribute__((ext_vector_type(4))) float  f32x4;
typedef __attribute__((ext_vector_type(2))) float  f32x2;

static __device__ __forceinline__ ushort f2bf(float f) {
    union { float f; unsigned u; } a; a.f = f;
    unsigned r = a.u + 0x7FFF + ((a.u >> 16) & 1);   // RNE to bf16
    return (ushort)(r >> 16);
}
static __device__ __forceinline__ float bf2f(ushort h) {
    union { unsigned u; float f; } a; a.u = (unsigned)h << 16;
    return a.f;
}

// ---------------------------------------------------------------------------
// Single fused kernel. Block = 1024 threads (16 waves) on one CU; grid = 256
// blocks = 1 block/CU. Block stages the FULL weighted z-panel (1024 rows ->
// 128 KB bf16, XOR-swizzled) + z2/alpha (8 KB) into LDS once. Each wave owns
// one 16-column x-strip (block covers 256 columns; zero cross-block
// redundancy: x converted exactly once chip-wide). Inner loop per tile:
// 2 swizzled ds_read_b128 (A) + 2 broadcast float4 reads (z2, alpha) +
// 2 chained MFMA + packed-f32 exp2 epilogue. Output written directly — no
// part buffer, no reduce kernel, no ws.
// Swizzle: byte colb ^= (row&7)<<4 on BOTH write and read (rule #21).
// Bank check per 16-lane phase (fixed g): offsets 16*(g^(p&7)) cover all 8
// slots -> 2-way only (free, m136). C/D: col = lane&15, row = 4*(lane>>4)+reg.
// ---------------------------------------------------------------------------
__global__ __launch_bounds__(1024) void igpr_fused(
        const float* __restrict__ x, const float* __restrict__ z,
        const float* __restrict__ alpha, const float* __restrict__ ls,
        float* __restrict__ out) {
    struct SM {
        uint4 zt[N_IND * 8];   // 1024 rows * 128 B = 128 KB (swizzled)
        float z2[N_IND];       // log2e * ||zw_i||^2
        float al[N_IND];       // alpha
        float wls[N_DESC];     // exp(-ls/2)
    };
    __shared__ SM sm;          // 136.25 KB of the CU's 160 KB

    const int tid  = threadIdx.x;
    const int lane = tid & 63;
    const int wave = tid >> 6;
    const int p = lane & 15;          // column within strip / z-row in tile
    const int g = lane >> 4;          // k-group
    const int j = blockIdx.x * 256 + wave * 16 + p;   // this lane's x column

    if (tid < N_DESC) sm.wls[tid] = __expf(-0.5f * ls[tid]);
    __syncthreads();   // wls ready

    // ---- stage full z-panel into LDS (f32 -> weighted bf16, swizzled) ----
    {
        char* zb = reinterpret_cast<char*>(sm.zt);
#pragma unroll
        for (int rb = 0; rb < 8; ++rb) {
            int lb  = rb * 1024 + tid;       // 16B-output-granule index
            int row = lb >> 3, gr = lb & 7;  // z-row, granule in row
            float4 v0 = *reinterpret_cast<const float4*>(&z[row * 64 + gr * 8]);
            float4 v1 = *reinterpret_cast<const float4*>(&z[row * 64 + gr * 8 + 4]);
            float vv[8] = {v0.x, v0.y, v0.z, v0.w, v1.x, v1.y, v1.z, v1.w};
            ushort hb[8];
            float sq = 0.f;
#pragma unroll
            for (int e = 0; e < 8; ++e) {
                ushort h = f2bf(vv[e] * sm.wls[gr * 8 + e]);
                hb[e] = h;
                float vr = bf2f(h);
                sq = fmaf(vr, vr, sq);
            }
            uint4 u = make_uint4(
                (unsigned)hb[0] | ((unsigned)hb[1] << 16),
                (unsigned)hb[2] | ((unsigned)hb[3] << 16),
                (unsigned)hb[4] | ((unsigned)hb[5] << 16),
                (unsigned)hb[6] | ((unsigned)hb[7] << 16));
            int sw = row * 128 + ((gr * 16) ^ ((row & 7) << 4));
            *reinterpret_cast<uint4*>(zb + sw) = u;
            // row-sum over the 8 granule-threads (xor partners within wave)
            sq += __shfl_xor(sq, 1);
            sq += __shfl_xor(sq, 2);
            sq += __shfl_xor(sq, 4);
            if (gr == 0) sm.z2[row] = sq * L2E;
        }
        sm.al[tid] = alpha[tid];   // N_IND == blockDim.x
    }

    // ---- B fragment (one 16-col strip) + log2e*x_sq, overlaps staging ----
    short8 b0, b1;
    float xs2;
    {
        const float* xr = x + (size_t)j * N_DESC;
        float sq = 0.f;
        short8 bb[2];
#pragma unroll
        for (int h = 0; h < 2; ++h) {
            float4 v0 = *reinterpret_cast<const float4*>(xr + h * 32 + g * 8);
            float4 v1 = *reinterpret_cast<const float4*>(xr + h * 32 + g * 8 + 4);
            float vv[8] = {v0.x, v0.y, v0.z, v0.w, v1.x, v1.y, v1.z, v1.w};
#pragma unroll
            for (int e = 0; e < 8; ++e) {
                ushort hh = f2bf(vv[e] * sm.wls[h * 32 + g * 8 + e]);
                bb[h][e] = (short)hh;
                float xv = bf2f(hh);
                sq = fmaf(xv, xv, sq);
            }
        }
        b0 = bb[0]; b1 = bb[1];
        sq += __shfl_xor(sq, 16);
        sq += __shfl_xor(sq, 32);
        xs2 = sq * L2E;
    }

    __syncthreads();   // z-panel ready (LDS read-only from here)

    const char* zb = reinterpret_cast<const char*>(sm.zt);
    const int rb0 = p * 128 + ((16 * g)      ^ ((p & 7) << 4));
    const int rb1 = p * 128 + ((64 + 16 * g) ^ ((p & 7) << 4));

    f32x2 accJ = {0.f, 0.f};

#pragma unroll 2
    for (int it = 0; it < TILES; ++it) {
        short8 a0 = *reinterpret_cast<const short8*>(zb + it * 2048 + rb0);
        short8 a1 = *reinterpret_cast<const short8*>(zb + it * 2048 + rb1);
        float4 z2 = *reinterpret_cast<const float4*>(&sm.z2[it * 16 + g * 4]);
        float4 a4 = *reinterpret_cast<const float4*>(&sm.al[it * 16 + g * 4]);

        f32x4 t = {0.f, 0.f, 0.f, 0.f};
        t = __builtin_amdgcn_mfma_f32_16x16x32_bf16(a0, b0, t, 0, 0, 0);
        t = __builtin_amdgcn_mfma_f32_16x16x32_bf16(a1, b1, t, 0, 0, 0);

        f32x2 z2p[2] = {{z2.x, z2.y}, {z2.z, z2.w}};
        f32x2 a4p[2] = {{a4.x, a4.y}, {a4.z, a4.w}};
        f32x2 xs2p = {xs2, xs2};
#pragma unroll
        for (int ep = 0; ep < 2; ++ep) {
            f32x2 dot2 = {t[2 * ep], t[2 * ep + 1]};
            f32x2 zx   = z2p[ep] + xs2p;               // v_pk_add_f32
            f32x2 arg  = dot2 * L2E2 - zx;             // contracts to pk_fma
            f32x2 pv   = {__builtin_amdgcn_exp2f(arg.x),
                          __builtin_amdgcn_exp2f(arg.y)};
            accJ = accJ + a4p[ep] * pv;                // contracts to pk_fma
        }
    }

    float r = accJ.x + accJ.y;
    r += __shfl_xor(r, 16);
    r += __shfl_xor(r, 32);
    if (g == 0) out[j] = r;
}

extern "C" void kernel_launch(void* const* d_in, const int* in_sizes, int n_in,
                              void* d_out, int out_size, void* d_ws, size_t ws_size,
                              hipStream_t stream) {
    const float* x     = (const float*)d_in[0];   // (65536, 64)
    const float* z     = (const float*)d_in[1];   // (1024, 64)
    const float* alpha = (const float*)d_in[2];   // (1024,)
    const float* ls    = (const float*)d_in[3];   // (64,)
    float* out = (float*)d_out;                   // (65536, 1)

    igpr_fused<<<dim3(N_X / 256), dim3(1024), 0, stream>>>(x, z, alpha, ls, out);
}